// Round 3
// baseline (168.437 us; speedup 1.0000x reference)
//
#include <hip/hip_runtime.h>
#include <math.h>

// Problem constants: B=32, N_SOURCES=262144, H=W=256
#define BATCH 32
#define NSRC  262144
#define HH    256
#define WW    256
#define HW    (HH * WW)
#define NBLK  16                 // partial-reduce blocks per batch

// ---------- ballot-binned path ----------
// 16 bands of 4096 px -> 16 KB acc LDS, 512 accum blocks (2/CU, 32 waves),
// direct stores (no combine). Arena bytes identical to the 8-band layout.
#define ZBANDS 16
#define ZBAND_PIX (HW / ZBANDS)    // 4096 px -> 16 KB acc LDS
#define ZCAP   18432               // mean 16384, sd ~124; +16 sd headroom
#define SPILL_CAP 131072
//   [0, 8192)        float4 partials[BATCH][NBLK]
//   [8192, 10240)    u32 cursors[BATCH*ZBANDS] (512)
//   [10240, 10244)   u32 spill_cnt
//   [16384, +1MB)    uint2 spill[SPILL_CAP]
//   [1064960, ...)   u32 arena[BATCH*ZBANDS][ZCAP]  entry = pix12 | bf16(pr)<<16
#define WS_ZCURS_OFF  8192
#define WS_ZSPCNT_OFF 10240
#define WS_ZSPILL_OFF 16384
#define WS_ZARENA_OFF (WS_ZSPILL_OFF + SPILL_CAP * 8)
#define WS_Z_BYTES    (WS_ZARENA_OFF + (size_t)BATCH * ZBANDS * ZCAP * 4)

#define FB_BANDS 8
#define FB_BAND_PIX (HW / FB_BANDS)

// ---------- Kernel A: per-batch bounding-box partials (+ zero small tables) ----------
__global__ void box_kernel(const float* __restrict__ spatial,
                           float4* __restrict__ partials,
                           unsigned int* __restrict__ zero_tab,  // may be null
                           int zero_n) {
    const int b   = blockIdx.y;
    const int blk = blockIdx.x;
    const int tid = threadIdx.x;  // 0..255

    if (zero_tab && blk == 0 && b == 0) {
        for (int j = tid; j < zero_n; j += 256) zero_tab[j] = 0u;
    }

    const int chunk = HW / NBLK;  // 4096
    const float* xs = spatial + (size_t)b * 2 * HW + (size_t)blk * chunk;
    const float* ys = xs + HW;

    float xmn = 1e30f, xmx = -1e30f, ymn = 1e30f, ymx = -1e30f;
    const float4* xs4 = (const float4*)xs;
    const float4* ys4 = (const float4*)ys;
#pragma unroll
    for (int k = 0; k < 4; k++) {
        float4 vx = xs4[k * 256 + tid];
        float4 vy = ys4[k * 256 + tid];
        xmn = fminf(xmn, fminf(fminf(vx.x, vx.y), fminf(vx.z, vx.w)));
        xmx = fmaxf(xmx, fmaxf(fmaxf(vx.x, vx.y), fmaxf(vx.z, vx.w)));
        ymn = fminf(ymn, fminf(fminf(vy.x, vy.y), fminf(vy.z, vy.w)));
        ymx = fmaxf(ymx, fmaxf(fmaxf(vy.x, vy.y), fmaxf(vy.z, vy.w)));
    }
#pragma unroll
    for (int off = 32; off > 0; off >>= 1) {
        xmn = fminf(xmn, __shfl_down(xmn, off));
        xmx = fmaxf(xmx, __shfl_down(xmx, off));
        ymn = fminf(ymn, __shfl_down(ymn, off));
        ymx = fmaxf(ymx, __shfl_down(ymx, off));
    }
    __shared__ float4 s[4];
    if ((tid & 63) == 0) s[tid >> 6] = make_float4(xmn, xmx, ymn, ymx);
    __syncthreads();
    if (tid == 0) {
        float4 r = s[0];
#pragma unroll
        for (int wv = 1; wv < 4; wv++) {
            float4 t = s[wv];
            r.x = fminf(r.x, t.x); r.y = fmaxf(r.y, t.y);
            r.z = fminf(r.z, t.z); r.w = fmaxf(r.w, t.w);
        }
        partials[b * NBLK + blk] = r;
    }
}

__device__ __forceinline__ float4 fold_box(const float4* __restrict__ partials,
                                           int b, int tid, float4* sbox) {
    if (tid < 64) {
        float4 p = make_float4(1e30f, -1e30f, 1e30f, -1e30f);
        if (tid < NBLK) p = partials[b * NBLK + tid];
        float xmn = p.x, xmx = p.y, ymn = p.z, ymx = p.w;
#pragma unroll
        for (int off = 8; off > 0; off >>= 1) {
            xmn = fminf(xmn, __shfl_down(xmn, off));
            xmx = fmaxf(xmx, __shfl_down(xmx, off));
            ymn = fminf(ymn, __shfl_down(ymn, off));
            ymx = fmaxf(ymx, __shfl_down(ymx, off));
        }
        if (tid == 0) *sbox = make_float4(xmn, xmx, ymn, ymx);
    }
    __syncthreads();
    return *sbox;
}

// Verified reference pipeline (R8): reciprocal-multiply, correctly-rounded f32,
// half-even rounding, clip to [0,255].
__device__ __forceinline__ int route_of(float cx, float cy, float xmin,
                                        float ymin, float invx, float invy) {
    const float nx = __fmul_rn(__fsub_rn(cx, xmin), invx);
    const float ny = __fmul_rn(__fsub_rn(cy, ymin), invy);
    int px = (int)rintf(__fmul_rn(nx, 255.0f));
    int py = (int)rintf(__fmul_rn(ny, 255.0f));
    px = px < 0 ? 0 : (px > 255 ? 255 : px);
    py = py < 0 ? 0 : (py > 255 ? 255 : py);
    return py * WW + px;
}

// ================= BALLOT-BINNED PATH =================
// Scatter: ranks via bit-sliced wave ballots (zero LDS atomics);
//          entry = pix12 | bf16(pr)<<16.
// Accum:   LDS atomicAdd of pr only (g factored out: out = g * sum(pr)).

__global__ __launch_bounds__(256) void scatter_ballot_kernel(
    const float* __restrict__ point_rates, const float2* __restrict__ coords,
    const float4* __restrict__ partials, unsigned int* __restrict__ cursors,
    unsigned int* __restrict__ arena, unsigned int* __restrict__ spill_cnt,
    uint2* __restrict__ spill) {
    const int b    = blockIdx.y;
    const int tid  = threadIdx.x;
    const int wave = tid >> 6;
    const int lane = tid & 63;
    __shared__ float4 sbox;
    __shared__ unsigned int wtot[4][ZBANDS];
    __shared__ unsigned int wbase[4][ZBANDS];

    const float4 box = fold_box(partials, b, tid, &sbox);
    const float xmin = box.x, xmax = box.y, ymin = box.z, ymax = box.w;
    const float invx = __fdiv_rn(1.0f, __fsub_rn(xmax, xmin));
    const float invy = __fdiv_rn(1.0f, __fsub_rn(ymax, ymin));

    const unsigned long long below =
        (lane == 63) ? 0x7FFFFFFFFFFFFFFFull : ((1ull << lane) - 1ull);

    const float* prb = point_rates + (size_t)b * NSRC;
    const int base = blockIdx.x * 4096;

    // lane-sliced running count: lane i holds the running total of bin (i&15)
    unsigned int cur_slice = 0u;

    unsigned int ent[16];
    unsigned int meta[16];  // (z<<16)|slot_in_wave, or 0xFFFFFFFF if skipped

#pragma unroll
    for (int k = 0; k < 16; k++) {
        const int i = base + k * 256 + tid;
        const float2 c = coords[i];
        const float  pr = prb[i];
        const bool valid =
            !(c.x < xmin || c.x > xmax || c.y < ymin || c.y > ymax);
        const int idx = route_of(c.x, c.y, xmin, ymin, invx, invy);
        const int z = valid ? (idx >> 12) : ZBANDS;  // band of 4096 px
        // f32 -> bf16 RNE of point_rate (>=0, finite)
        const unsigned int bits = __float_as_uint(pr);
        const unsigned int b16 = (bits + 0x7FFFu + ((bits >> 16) & 1u)) >> 16;
        ent[k] = (unsigned int)(idx & (ZBAND_PIX - 1)) | (b16 << 16);

        // Bit-sliced ballot ranking: 5 ballots cover all 16 bins.
        const unsigned long long bv = __ballot(valid);
        const unsigned long long b0 = __ballot((z & 1) != 0);
        const unsigned long long b1 = __ballot((z & 2) != 0);
        const unsigned long long b2 = __ballot((z & 4) != 0);
        const unsigned long long b3 = __ballot((z & 8) != 0);
        // lane i materializes the member-mask of bin (i&15)
        unsigned long long m = bv;
        m &= (lane & 1) ? b0 : ~b0;
        m &= (lane & 2) ? b1 : ~b1;
        m &= (lane & 4) ? b2 : ~b2;
        m &= (lane & 8) ? b3 : ~b3;
        const unsigned int cnt = (unsigned int)__popcll(m);
        // fetch own-bin running base and own-bin mask from lane z (pre-update)
        const unsigned int curbase = __shfl(cur_slice, z);
        const unsigned long long mown = __shfl(m, z);
        const unsigned int rank = (unsigned int)__popcll(mown & below);
        meta[k] = valid ? (((unsigned int)z << 16) | (curbase + rank))
                        : 0xFFFFFFFFu;
        cur_slice += cnt;
    }

    // publish per-wave totals (non-atomic: each wave owns its row)
    if (lane < ZBANDS) wtot[wave][lane] = cur_slice;
    __syncthreads();

    // wave 0, lane z<16: fold 4 waves, reserve global range, compute wave bases
    if (wave == 0 && lane < ZBANDS) {
        unsigned int t0 = wtot[0][lane], t1 = wtot[1][lane],
                     t2 = wtot[2][lane], t3 = wtot[3][lane];
        unsigned int tot = t0 + t1 + t2 + t3;
        unsigned int g = atomicAdd(&cursors[b * ZBANDS + lane], tot);
        wbase[0][lane] = g;
        wbase[1][lane] = g + t0;
        wbase[2][lane] = g + t0 + t1;
        wbase[3][lane] = g + t0 + t1 + t2;
    }
    __syncthreads();

#pragma unroll
    for (int k = 0; k < 16; k++) {
        const unsigned int mt = meta[k];
        if (mt == 0xFFFFFFFFu) continue;
        const unsigned int z = mt >> 16;
        const unsigned int slot = wbase[wave][z] + (mt & 0xFFFFu);
        if (slot < ZCAP) {
            arena[((size_t)b * ZBANDS + z) * ZCAP + slot] = ent[k];
        } else {
            // bin overflow (pathological distribution): spill globally
            const unsigned int pos = atomicAdd(spill_cnt, 1u);
            if (pos < SPILL_CAP) {
                const unsigned int pix =
                    (z << 12) | (ent[k] & (ZBAND_PIX - 1));
                const int i = base + k * 256 + tid;
                spill[pos] = make_uint2(((unsigned int)b << 16) | pix,
                                        __float_as_uint(prb[i]));
            }
        }
    }
}

// R3: force 4-deep MLP. R0/R2 both ran at 512 B outstanding/CU (VGPR_Count=8
// proved the allocator serialized the batched loads); duration was invariant
// to occupancy => latency-bound at allocator-imposed MLP. The empty asm pins
// all 16 load components live so 4 global_load_dwordx4 issue back-to-back.
__global__ __launch_bounds__(1024) void accum_g_kernel(
    const unsigned int* __restrict__ arena, const float* __restrict__ gia,
    const unsigned int* __restrict__ cursors, float* __restrict__ out) {
    __shared__ float acc[ZBAND_PIX];  // 16 KB
    const int z   = blockIdx.x;
    const int b   = blockIdx.y;
    const int tid = threadIdx.x;  // 0..1023

    // issue long-latency reads for cursor + epilogue gia before the LDS work
    const unsigned int n_raw = cursors[b * ZBANDS + z];
    const float4* g4 =
        (const float4*)(gia + (size_t)b * HW + (size_t)z * ZBAND_PIX);
    float4 g = g4[tid];
    asm volatile("" : "+v"(g.x), "+v"(g.y), "+v"(g.z), "+v"(g.w));

    ((float4*)acc)[tid] = make_float4(0.f, 0.f, 0.f, 0.f);  // 4096 floats
    __syncthreads();

    unsigned int n = n_raw;
    if (n > ZCAP) n = ZCAP;
    const uint4* a4 = (const uint4*)(arena + ((size_t)b * ZBANDS + z) * ZCAP);

    // entry = pix12 | bf16(pr)<<16 ; accumulate pr only (g factored out)
#define DO_E(w)                                                              \
    atomicAdd(&acc[(w) & (ZBAND_PIX - 1)],                                   \
              __uint_as_float((w) & 0xFFFF0000u));
    const unsigned int n4 = n >> 2;
    unsigned int j = tid;
    // typical n4 ~= 4096: every thread does exactly one 4-deep iteration
    for (; j + 3u * 1024u < n4; j += 4u * 1024u) {
        uint4 e0 = a4[j];
        uint4 e1 = a4[j + 1024u];
        uint4 e2 = a4[j + 2048u];
        uint4 e3 = a4[j + 3072u];
        // pin all 16 dwords live -> compiler must issue the 4 loads in flight
        asm volatile(""
                     : "+v"(e0.x), "+v"(e0.y), "+v"(e0.z), "+v"(e0.w),
                       "+v"(e1.x), "+v"(e1.y), "+v"(e1.z), "+v"(e1.w),
                       "+v"(e2.x), "+v"(e2.y), "+v"(e2.z), "+v"(e2.w),
                       "+v"(e3.x), "+v"(e3.y), "+v"(e3.z), "+v"(e3.w));
        DO_E(e0.x) DO_E(e0.y) DO_E(e0.z) DO_E(e0.w)
        DO_E(e1.x) DO_E(e1.y) DO_E(e1.z) DO_E(e1.w)
        DO_E(e2.x) DO_E(e2.y) DO_E(e2.z) DO_E(e2.w)
        DO_E(e3.x) DO_E(e3.y) DO_E(e3.z) DO_E(e3.w)
    }
    for (; j < n4; j += 1024u) {
        const uint4 e = a4[j];
        DO_E(e.x) DO_E(e.y) DO_E(e.z) DO_E(e.w)
    }
    const unsigned int* a1 = (const unsigned int*)a4;
    for (unsigned int jj = (n4 << 2) + tid; jj < n; jj += 1024u) {
        const unsigned int w = a1[jj];
        DO_E(w)
    }
#undef DO_E
    __syncthreads();

    // out = acc * g, coalesced direct store (block exclusively owns band)
    float4* o4 = (float4*)(out + (size_t)b * HW + (size_t)z * ZBAND_PIX);
    const float4 a = ((const float4*)acc)[tid];
    o4[tid] = make_float4(__fmul_rn(a.x, g.x), __fmul_rn(a.y, g.y),
                          __fmul_rn(a.z, g.z), __fmul_rn(a.w, g.w));
}

__global__ void spill_kernel(const unsigned int* __restrict__ spill_cnt,
                             const uint2* __restrict__ spill,
                             const float* __restrict__ gia,
                             float* __restrict__ out) {
    unsigned int n = *spill_cnt;
    if (n > SPILL_CAP) n = SPILL_CAP;
    for (unsigned int j = blockIdx.x * 256 + threadIdx.x; j < n;
         j += gridDim.x * 256) {
        const uint2 e = spill[j];
        const unsigned int b = e.x >> 16;
        const unsigned int pix = e.x & 0xFFFFu;
        const float pr = __uint_as_float(e.y);
        atomicAdd(&out[(size_t)b * HW + pix],
                  __fmul_rn(pr, gia[(size_t)b * HW + pix]));
    }
}

// ================= FALLBACK (exact, small-ws) =================

__global__ __launch_bounds__(512) void accum_recompute_kernel(
    const float* __restrict__ point_rates, const float* __restrict__ gia,
    const float2* __restrict__ coords, const float4* __restrict__ partials,
    float* __restrict__ out) {
    __shared__ float acc[FB_BAND_PIX];
    __shared__ float4 sbox;
    const int z   = blockIdx.x;
    const int b   = blockIdx.y;
    const int tid = threadIdx.x;

    const float4 box = fold_box(partials, b, tid, &sbox);
    const float xmin = box.x, xmax = box.y, ymin = box.z, ymax = box.w;
    const float invx = __fdiv_rn(1.0f, __fsub_rn(xmax, xmin));
    const float invy = __fdiv_rn(1.0f, __fsub_rn(ymax, ymin));

    for (int j = tid; j < FB_BAND_PIX; j += 512) acc[j] = 0.f;
    __syncthreads();

    const float* prb = point_rates + (size_t)b * NSRC;
    const float* gb  = gia + (size_t)b * HW;
    const int lo = z * FB_BAND_PIX, hi = lo + FB_BAND_PIX;

    for (int i = tid; i < NSRC; i += 512) {
        const float2 c = coords[i];
        if (c.x < xmin || c.x > xmax || c.y < ymin || c.y > ymax) continue;
        const int idx = route_of(c.x, c.y, xmin, ymin, invx, invy);
        if (idx < lo || idx >= hi) continue;
        const float em = __fmul_rn(prb[i], gb[idx]);
        atomicAdd(&acc[idx - lo], em);
    }
    __syncthreads();

    float4* o4 = (float4*)(out + (size_t)b * HW + (size_t)z * FB_BAND_PIX);
    const float4* a4 = (const float4*)acc;
    for (int j = tid; j < FB_BAND_PIX / 4; j += 512) o4[j] = a4[j];
}

extern "C" void kernel_launch(void* const* d_in, const int* in_sizes, int n_in,
                              void* d_out, int out_size, void* d_ws, size_t ws_size,
                              hipStream_t stream) {
    const float* point_rates = (const float*)d_in[0];   // (B, NSRC)
    const float* spatial     = (const float*)d_in[1];   // (B, 2, H, W)
    const float* gia         = (const float*)d_in[2];   // (B, H, W)
    const float2* coords     = (const float2*)d_in[3];  // (NSRC, 2)
    float* out = (float*)d_out;                         // (B, 1, H, W)

    char* ws = (char*)d_ws;
    float4* partials = (float4*)ws;

    if (ws_size >= WS_Z_BYTES) {
        unsigned int* cursors   = (unsigned int*)(ws + WS_ZCURS_OFF);
        unsigned int* spill_cnt = (unsigned int*)(ws + WS_ZSPCNT_OFF);
        uint2*        spill     = (uint2*)(ws + WS_ZSPILL_OFF);
        unsigned int* arena     = (unsigned int*)(ws + WS_ZARENA_OFF);

        // cursors (512 u32) + spill_cnt contiguous: zero 513 u32
        box_kernel<<<dim3(NBLK, BATCH), 256, 0, stream>>>(
            spatial, partials, cursors, BATCH * ZBANDS + 1);
        scatter_ballot_kernel<<<dim3(NSRC / 4096, BATCH), 256, 0, stream>>>(
            point_rates, coords, partials, cursors, arena, spill_cnt, spill);
        accum_g_kernel<<<dim3(ZBANDS, BATCH), 1024, 0, stream>>>(
            arena, gia, cursors, out);
        spill_kernel<<<4, 256, 0, stream>>>(spill_cnt, spill, gia, out);
    } else {
        box_kernel<<<dim3(NBLK, BATCH), 256, 0, stream>>>(
            spatial, partials, nullptr, 0);
        accum_recompute_kernel<<<dim3(FB_BANDS, BATCH), 512, 0, stream>>>(
            point_rates, gia, coords, partials, out);
    }
}

// Round 4
// 125.992 us; speedup vs baseline: 1.3369x; 1.3369x over previous
//
#include <hip/hip_runtime.h>
#include <math.h>

// Problem constants: B=32, N_SOURCES=262144, H=W=256
#define BATCH 32
#define NSRC  262144
#define HH    256
#define WW    256
#define HW    (HH * WW)
#define NBLK  16                 // partial-reduce blocks per batch

// ---------- ballot-binned path ----------
// 16 bands of 4096 px -> 16 KB acc LDS, 512 accum blocks (2/CU, 32 waves),
// direct stores (no combine).
// R4: integer fixed-point accumulation. entry = fixed20(pr)<<12 | pix12 with
// fixed = round(pr * 2^19); accum uses native ds_add_u32 (f32 LDS atomicAdd
// was ~3.5 cy/lane across R0-R3 => CAS-loop suspicion). Per-pixel sums
// <= ~40*2^19 ~ 2e7 << 2^32; quantization err ~1e-6/entry (better than bf16).
#define ZBANDS 16
#define ZBAND_PIX (HW / ZBANDS)    // 4096 px -> 16 KB acc LDS
#define ZCAP   18432               // mean 16384, sd ~124; +16 sd headroom
#define SPILL_CAP 131072
#define FIX_SCALE 524288.0f        // 2^19
#define FIX_INV   (1.0f / 524288.0f)
//   [0, 8192)        float4 partials[BATCH][NBLK]
//   [8192, 10240)    u32 cursors[BATCH*ZBANDS] (512)
//   [10240, 10244)   u32 spill_cnt
//   [16384, +1MB)    uint2 spill[SPILL_CAP]
//   [1064960, ...)   u32 arena[BATCH*ZBANDS][ZCAP]  entry = fixed20<<12 | pix12
#define WS_ZCURS_OFF  8192
#define WS_ZSPCNT_OFF 10240
#define WS_ZSPILL_OFF 16384
#define WS_ZARENA_OFF (WS_ZSPILL_OFF + SPILL_CAP * 8)
#define WS_Z_BYTES    (WS_ZARENA_OFF + (size_t)BATCH * ZBANDS * ZCAP * 4)

#define FB_BANDS 8
#define FB_BAND_PIX (HW / FB_BANDS)

// ---------- Kernel A: per-batch bounding-box partials (+ zero small tables) ----------
__global__ void box_kernel(const float* __restrict__ spatial,
                           float4* __restrict__ partials,
                           unsigned int* __restrict__ zero_tab,  // may be null
                           int zero_n) {
    const int b   = blockIdx.y;
    const int blk = blockIdx.x;
    const int tid = threadIdx.x;  // 0..255

    if (zero_tab && blk == 0 && b == 0) {
        for (int j = tid; j < zero_n; j += 256) zero_tab[j] = 0u;
    }

    const int chunk = HW / NBLK;  // 4096
    const float* xs = spatial + (size_t)b * 2 * HW + (size_t)blk * chunk;
    const float* ys = xs + HW;

    float xmn = 1e30f, xmx = -1e30f, ymn = 1e30f, ymx = -1e30f;
    const float4* xs4 = (const float4*)xs;
    const float4* ys4 = (const float4*)ys;
#pragma unroll
    for (int k = 0; k < 4; k++) {
        float4 vx = xs4[k * 256 + tid];
        float4 vy = ys4[k * 256 + tid];
        xmn = fminf(xmn, fminf(fminf(vx.x, vx.y), fminf(vx.z, vx.w)));
        xmx = fmaxf(xmx, fmaxf(fmaxf(vx.x, vx.y), fmaxf(vx.z, vx.w)));
        ymn = fminf(ymn, fminf(fminf(vy.x, vy.y), fminf(vy.z, vy.w)));
        ymx = fmaxf(ymx, fmaxf(fmaxf(vy.x, vy.y), fmaxf(vy.z, vy.w)));
    }
#pragma unroll
    for (int off = 32; off > 0; off >>= 1) {
        xmn = fminf(xmn, __shfl_down(xmn, off));
        xmx = fmaxf(xmx, __shfl_down(xmx, off));
        ymn = fminf(ymn, __shfl_down(ymn, off));
        ymx = fmaxf(ymx, __shfl_down(ymx, off));
    }
    __shared__ float4 s[4];
    if ((tid & 63) == 0) s[tid >> 6] = make_float4(xmn, xmx, ymn, ymx);
    __syncthreads();
    if (tid == 0) {
        float4 r = s[0];
#pragma unroll
        for (int wv = 1; wv < 4; wv++) {
            float4 t = s[wv];
            r.x = fminf(r.x, t.x); r.y = fmaxf(r.y, t.y);
            r.z = fminf(r.z, t.z); r.w = fmaxf(r.w, t.w);
        }
        partials[b * NBLK + blk] = r;
    }
}

__device__ __forceinline__ float4 fold_box(const float4* __restrict__ partials,
                                           int b, int tid, float4* sbox) {
    if (tid < 64) {
        float4 p = make_float4(1e30f, -1e30f, 1e30f, -1e30f);
        if (tid < NBLK) p = partials[b * NBLK + tid];
        float xmn = p.x, xmx = p.y, ymn = p.z, ymx = p.w;
#pragma unroll
        for (int off = 8; off > 0; off >>= 1) {
            xmn = fminf(xmn, __shfl_down(xmn, off));
            xmx = fmaxf(xmx, __shfl_down(xmx, off));
            ymn = fminf(ymn, __shfl_down(ymn, off));
            ymx = fmaxf(ymx, __shfl_down(ymx, off));
        }
        if (tid == 0) *sbox = make_float4(xmn, xmx, ymn, ymx);
    }
    __syncthreads();
    return *sbox;
}

// Verified reference pipeline (R8): reciprocal-multiply, correctly-rounded f32,
// half-even rounding, clip to [0,255].
__device__ __forceinline__ int route_of(float cx, float cy, float xmin,
                                        float ymin, float invx, float invy) {
    const float nx = __fmul_rn(__fsub_rn(cx, xmin), invx);
    const float ny = __fmul_rn(__fsub_rn(cy, ymin), invy);
    int px = (int)rintf(__fmul_rn(nx, 255.0f));
    int py = (int)rintf(__fmul_rn(ny, 255.0f));
    px = px < 0 ? 0 : (px > 255 ? 255 : px);
    py = py < 0 ? 0 : (py > 255 ? 255 : py);
    return py * WW + px;
}

// ================= BALLOT-BINNED PATH =================
// Scatter: ranks via bit-sliced wave ballots (zero LDS atomics);
//          entry = fixed20(pr)<<12 | pix12.
// Accum:   native u32 LDS atomicAdd of fixed-point pr (g factored out).

__global__ __launch_bounds__(256) void scatter_ballot_kernel(
    const float* __restrict__ point_rates, const float2* __restrict__ coords,
    const float4* __restrict__ partials, unsigned int* __restrict__ cursors,
    unsigned int* __restrict__ arena, unsigned int* __restrict__ spill_cnt,
    uint2* __restrict__ spill) {
    const int b    = blockIdx.y;
    const int tid  = threadIdx.x;
    const int wave = tid >> 6;
    const int lane = tid & 63;
    __shared__ float4 sbox;
    __shared__ unsigned int wtot[4][ZBANDS];
    __shared__ unsigned int wbase[4][ZBANDS];

    const float4 box = fold_box(partials, b, tid, &sbox);
    const float xmin = box.x, xmax = box.y, ymin = box.z, ymax = box.w;
    const float invx = __fdiv_rn(1.0f, __fsub_rn(xmax, xmin));
    const float invy = __fdiv_rn(1.0f, __fsub_rn(ymax, ymin));

    const unsigned long long below =
        (lane == 63) ? 0x7FFFFFFFFFFFFFFFull : ((1ull << lane) - 1ull);

    const float* prb = point_rates + (size_t)b * NSRC;
    const int base = blockIdx.x * 4096;

    // lane-sliced running count: lane i holds the running total of bin (i&15)
    unsigned int cur_slice = 0u;

    unsigned int ent[16];
    unsigned int meta[16];  // (z<<16)|slot_in_wave, or 0xFFFFFFFF if skipped

#pragma unroll
    for (int k = 0; k < 16; k++) {
        const int i = base + k * 256 + tid;
        const float2 c = coords[i];
        const float  pr = prb[i];
        const bool valid =
            !(c.x < xmin || c.x > xmax || c.y < ymin || c.y > ymax);
        const int idx = route_of(c.x, c.y, xmin, ymin, invx, invy);
        const int z = valid ? (idx >> 12) : ZBANDS;  // band of 4096 px
        // f32 -> fixed-point (scale 2^19, round-to-nearest); pr in [0,1]
        const unsigned int fixed =
            (unsigned int)(__fmul_rn(pr, FIX_SCALE) + 0.5f);
        ent[k] = (unsigned int)(idx & (ZBAND_PIX - 1)) | (fixed << 12);

        // Bit-sliced ballot ranking: 5 ballots cover all 16 bins.
        const unsigned long long bv = __ballot(valid);
        const unsigned long long b0 = __ballot((z & 1) != 0);
        const unsigned long long b1 = __ballot((z & 2) != 0);
        const unsigned long long b2 = __ballot((z & 4) != 0);
        const unsigned long long b3 = __ballot((z & 8) != 0);
        // lane i materializes the member-mask of bin (i&15)
        unsigned long long m = bv;
        m &= (lane & 1) ? b0 : ~b0;
        m &= (lane & 2) ? b1 : ~b1;
        m &= (lane & 4) ? b2 : ~b2;
        m &= (lane & 8) ? b3 : ~b3;
        const unsigned int cnt = (unsigned int)__popcll(m);
        // fetch own-bin running base and own-bin mask from lane z (pre-update)
        const unsigned int curbase = __shfl(cur_slice, z);
        const unsigned long long mown = __shfl(m, z);
        const unsigned int rank = (unsigned int)__popcll(mown & below);
        meta[k] = valid ? (((unsigned int)z << 16) | (curbase + rank))
                        : 0xFFFFFFFFu;
        cur_slice += cnt;
    }

    // publish per-wave totals (non-atomic: each wave owns its row)
    if (lane < ZBANDS) wtot[wave][lane] = cur_slice;
    __syncthreads();

    // wave 0, lane z<16: fold 4 waves, reserve global range, compute wave bases
    if (wave == 0 && lane < ZBANDS) {
        unsigned int t0 = wtot[0][lane], t1 = wtot[1][lane],
                     t2 = wtot[2][lane], t3 = wtot[3][lane];
        unsigned int tot = t0 + t1 + t2 + t3;
        unsigned int g = atomicAdd(&cursors[b * ZBANDS + lane], tot);
        wbase[0][lane] = g;
        wbase[1][lane] = g + t0;
        wbase[2][lane] = g + t0 + t1;
        wbase[3][lane] = g + t0 + t1 + t2;
    }
    __syncthreads();

#pragma unroll
    for (int k = 0; k < 16; k++) {
        const unsigned int mt = meta[k];
        if (mt == 0xFFFFFFFFu) continue;
        const unsigned int z = mt >> 16;
        const unsigned int slot = wbase[wave][z] + (mt & 0xFFFFu);
        if (slot < ZCAP) {
            arena[((size_t)b * ZBANDS + z) * ZCAP + slot] = ent[k];
        } else {
            // bin overflow (pathological distribution): spill globally
            const unsigned int pos = atomicAdd(spill_cnt, 1u);
            if (pos < SPILL_CAP) {
                const unsigned int pix =
                    (z << 12) | (ent[k] & (ZBAND_PIX - 1));
                const int i = base + k * 256 + tid;
                spill[pos] = make_uint2(((unsigned int)b << 16) | pix,
                                        __float_as_uint(prb[i]));
            }
        }
    }
}

// R4: u32 fixed-point LDS accumulation (native ds_add_u32). R0-R3 showed the
// f32 LDS atomicAdd phase pinned at ~48us (=3.5 cy/lane-atomic) invariant to
// occupancy (R2) and global-load MLP (R3, VGPR 8->20) => suspected CAS-loop
// lowering of f32 shared atomics. Integer atomics are unambiguously native.
__global__ __launch_bounds__(1024) void accum_g_kernel(
    const unsigned int* __restrict__ arena, const float* __restrict__ gia,
    const unsigned int* __restrict__ cursors, float* __restrict__ out) {
    __shared__ unsigned int acc[ZBAND_PIX];  // 16 KB
    const int z   = blockIdx.x;
    const int b   = blockIdx.y;
    const int tid = threadIdx.x;  // 0..1023

    // issue long-latency reads for cursor + epilogue gia before the LDS work
    const unsigned int n_raw = cursors[b * ZBANDS + z];
    const float4* g4 =
        (const float4*)(gia + (size_t)b * HW + (size_t)z * ZBAND_PIX);
    float4 g = g4[tid];
    asm volatile("" : "+v"(g.x), "+v"(g.y), "+v"(g.z), "+v"(g.w));

    ((uint4*)acc)[tid] = make_uint4(0u, 0u, 0u, 0u);  // 4096 words
    __syncthreads();

    unsigned int n = n_raw;
    if (n > ZCAP) n = ZCAP;
    const uint4* a4 = (const uint4*)(arena + ((size_t)b * ZBANDS + z) * ZCAP);

    // entry = fixed20<<12 | pix12 ; accumulate fixed-point pr (g factored out)
#define DO_E(w)                                                              \
    atomicAdd(&acc[(w) & (ZBAND_PIX - 1)], (w) >> 12);
    const unsigned int n4 = n >> 2;
    unsigned int j = tid;
    // typical n4 ~= 4096: every thread does exactly one 4-deep iteration
    for (; j + 3u * 1024u < n4; j += 4u * 1024u) {
        uint4 e0 = a4[j];
        uint4 e1 = a4[j + 1024u];
        uint4 e2 = a4[j + 2048u];
        uint4 e3 = a4[j + 3072u];
        // pin all 16 dwords live -> compiler must issue the 4 loads in flight
        asm volatile(""
                     : "+v"(e0.x), "+v"(e0.y), "+v"(e0.z), "+v"(e0.w),
                       "+v"(e1.x), "+v"(e1.y), "+v"(e1.z), "+v"(e1.w),
                       "+v"(e2.x), "+v"(e2.y), "+v"(e2.z), "+v"(e2.w),
                       "+v"(e3.x), "+v"(e3.y), "+v"(e3.z), "+v"(e3.w));
        DO_E(e0.x) DO_E(e0.y) DO_E(e0.z) DO_E(e0.w)
        DO_E(e1.x) DO_E(e1.y) DO_E(e1.z) DO_E(e1.w)
        DO_E(e2.x) DO_E(e2.y) DO_E(e2.z) DO_E(e2.w)
        DO_E(e3.x) DO_E(e3.y) DO_E(e3.z) DO_E(e3.w)
    }
    for (; j < n4; j += 1024u) {
        const uint4 e = a4[j];
        DO_E(e.x) DO_E(e.y) DO_E(e.z) DO_E(e.w)
    }
    const unsigned int* a1 = (const unsigned int*)a4;
    for (unsigned int jj = (n4 << 2) + tid; jj < n; jj += 1024u) {
        const unsigned int w = a1[jj];
        DO_E(w)
    }
#undef DO_E
    __syncthreads();

    // out = acc * 2^-19 * g, coalesced direct store (block owns band)
    float4* o4 = (float4*)(out + (size_t)b * HW + (size_t)z * ZBAND_PIX);
    const uint4 a = ((const uint4*)acc)[tid];
    o4[tid] = make_float4(
        __fmul_rn(__fmul_rn((float)a.x, FIX_INV), g.x),
        __fmul_rn(__fmul_rn((float)a.y, FIX_INV), g.y),
        __fmul_rn(__fmul_rn((float)a.z, FIX_INV), g.z),
        __fmul_rn(__fmul_rn((float)a.w, FIX_INV), g.w));
}

__global__ void spill_kernel(const unsigned int* __restrict__ spill_cnt,
                             const uint2* __restrict__ spill,
                             const float* __restrict__ gia,
                             float* __restrict__ out) {
    unsigned int n = *spill_cnt;
    if (n > SPILL_CAP) n = SPILL_CAP;
    for (unsigned int j = blockIdx.x * 256 + threadIdx.x; j < n;
         j += gridDim.x * 256) {
        const uint2 e = spill[j];
        const unsigned int b = e.x >> 16;
        const unsigned int pix = e.x & 0xFFFFu;
        const float pr = __uint_as_float(e.y);
        atomicAdd(&out[(size_t)b * HW + pix],
                  __fmul_rn(pr, gia[(size_t)b * HW + pix]));
    }
}

// ================= FALLBACK (exact, small-ws) =================

__global__ __launch_bounds__(512) void accum_recompute_kernel(
    const float* __restrict__ point_rates, const float* __restrict__ gia,
    const float2* __restrict__ coords, const float4* __restrict__ partials,
    float* __restrict__ out) {
    __shared__ float acc[FB_BAND_PIX];
    __shared__ float4 sbox;
    const int z   = blockIdx.x;
    const int b   = blockIdx.y;
    const int tid = threadIdx.x;

    const float4 box = fold_box(partials, b, tid, &sbox);
    const float xmin = box.x, xmax = box.y, ymin = box.z, ymax = box.w;
    const float invx = __fdiv_rn(1.0f, __fsub_rn(xmax, xmin));
    const float invy = __fdiv_rn(1.0f, __fsub_rn(ymax, ymin));

    for (int j = tid; j < FB_BAND_PIX; j += 512) acc[j] = 0.f;
    __syncthreads();

    const float* prb = point_rates + (size_t)b * NSRC;
    const float* gb  = gia + (size_t)b * HW;
    const int lo = z * FB_BAND_PIX, hi = lo + FB_BAND_PIX;

    for (int i = tid; i < NSRC; i += 512) {
        const float2 c = coords[i];
        if (c.x < xmin || c.x > xmax || c.y < ymin || c.y > ymax) continue;
        const int idx = route_of(c.x, c.y, xmin, ymin, invx, invy);
        if (idx < lo || idx >= hi) continue;
        const float em = __fmul_rn(prb[i], gb[idx]);
        atomicAdd(&acc[idx - lo], em);
    }
    __syncthreads();

    float4* o4 = (float4*)(out + (size_t)b * HW + (size_t)z * FB_BAND_PIX);
    const float4* a4 = (const float4*)acc;
    for (int j = tid; j < FB_BAND_PIX / 4; j += 512) o4[j] = a4[j];
}

extern "C" void kernel_launch(void* const* d_in, const int* in_sizes, int n_in,
                              void* d_out, int out_size, void* d_ws, size_t ws_size,
                              hipStream_t stream) {
    const float* point_rates = (const float*)d_in[0];   // (B, NSRC)
    const float* spatial     = (const float*)d_in[1];   // (B, 2, H, W)
    const float* gia         = (const float*)d_in[2];   // (B, H, W)
    const float2* coords     = (const float2*)d_in[3];  // (NSRC, 2)
    float* out = (float*)d_out;                         // (B, 1, H, W)

    char* ws = (char*)d_ws;
    float4* partials = (float4*)ws;

    if (ws_size >= WS_Z_BYTES) {
        unsigned int* cursors   = (unsigned int*)(ws + WS_ZCURS_OFF);
        unsigned int* spill_cnt = (unsigned int*)(ws + WS_ZSPCNT_OFF);
        uint2*        spill     = (uint2*)(ws + WS_ZSPILL_OFF);
        unsigned int* arena     = (unsigned int*)(ws + WS_ZARENA_OFF);

        // cursors (512 u32) + spill_cnt contiguous: zero 513 u32
        box_kernel<<<dim3(NBLK, BATCH), 256, 0, stream>>>(
            spatial, partials, cursors, BATCH * ZBANDS + 1);
        scatter_ballot_kernel<<<dim3(NSRC / 4096, BATCH), 256, 0, stream>>>(
            point_rates, coords, partials, cursors, arena, spill_cnt, spill);
        accum_g_kernel<<<dim3(ZBANDS, BATCH), 1024, 0, stream>>>(
            arena, gia, cursors, out);
        spill_kernel<<<4, 256, 0, stream>>>(spill_cnt, spill, gia, out);
    } else {
        box_kernel<<<dim3(NBLK, BATCH), 256, 0, stream>>>(
            spatial, partials, nullptr, 0);
        accum_recompute_kernel<<<dim3(FB_BANDS, BATCH), 512, 0, stream>>>(
            point_rates, gia, coords, partials, out);
    }
}